// Round 1
// baseline (300.283 us; speedup 1.0000x reference)
//
#include <hip/hip_runtime.h>
#include <hip/hip_bf16.h>

#define T_DIM 2048
#define B_DIM 2
#define E_DIM 1024
#define H_DIM 16
#define D_DIM 64

typedef __attribute__((ext_vector_type(8))) short short8_t;
typedef short8_t __attribute__((may_alias)) short8_a;
typedef __attribute__((ext_vector_type(4))) short short4_t;
typedef short4_t __attribute__((may_alias)) short4_a;
typedef __attribute__((ext_vector_type(4))) float f32x4;
typedef __attribute__((ext_vector_type(4))) float float4_t;
typedef float4_t __attribute__((may_alias)) float4_a;

__device__ __forceinline__ short f2bf(float f) {
    unsigned int u = __builtin_bit_cast(unsigned int, f);
    unsigned int r = (u + 0x7fffu + ((u >> 16) & 1u)) >> 16;
    return (short)r;
}

// ---------------- fp32 -> bf16 cast ----------------
__global__ __launch_bounds__(256) void cvt_kernel(const float* __restrict__ in,
                                                  short* __restrict__ out, int n) {
    int i = (blockIdx.x * 256 + threadIdx.x) * 8;
    if (i >= n) return;
    float4_a a = *(const float4_a*)(in + i);
    float4_a b = *(const float4_a*)(in + i + 4);
    short8_a r;
    r[0] = f2bf(a[0]); r[1] = f2bf(a[1]); r[2] = f2bf(a[2]); r[3] = f2bf(a[3]);
    r[4] = f2bf(b[0]); r[5] = f2bf(b[1]); r[6] = f2bf(b[2]); r[7] = f2bf(b[3]);
    *(short8_a*)(out + i) = r;
}

// ---------------- projection GEMM ----------------
// C[m,n] = sum_k A[m,k] * W[n,k]  (NT form; A [4096,1024], W [1024,1024] both row-major bf16)
// MODE 0: Q -> [B,H,T,D] bf16, (acc+bias)*0.125
// MODE 1: K -> [B,H,T,D] bf16
// MODE 2: V -> [B,H,D,T] bf16 (transposed store)
// MODE 3: O -> [T,B,E] fp32
template <int MODE>
__global__ __launch_bounds__(256) void gemm_proj(const short* __restrict__ A,
                                                 const short* __restrict__ W,
                                                 const float* __restrict__ bias,
                                                 void* __restrict__ out) {
    __shared__ short As[128 * 40];  // rows padded to 40 shorts (80B) -> 2-way bank conflict (free)
    __shared__ short Bs[128 * 40];

    const int tid = threadIdx.x;
    const int l = tid & 63, w = tid >> 6;
    const int wm = w >> 1, wn = w & 1;
    const int m0 = blockIdx.y * 128, n0 = blockIdx.x * 128;
    const int l15 = l & 15, l4 = l >> 4;

    f32x4 acc[4][4];
#pragma unroll
    for (int i = 0; i < 4; i++)
#pragma unroll
        for (int j = 0; j < 4; j++) {
            f32x4 z = {0.f, 0.f, 0.f, 0.f};
            acc[i][j] = z;
        }

    for (int k0 = 0; k0 < 1024; k0 += 32) {
        __syncthreads();
#pragma unroll
        for (int r = 0; r < 2; r++) {
            int idx = tid + r * 256;
            int row = idx >> 2, ch = idx & 3;
            *(short8_a*)&As[row * 40 + ch * 8] =
                *(const short8_a*)&A[(m0 + row) * 1024 + k0 + ch * 8];
            *(short8_a*)&Bs[row * 40 + ch * 8] =
                *(const short8_a*)&W[(n0 + row) * 1024 + k0 + ch * 8];
        }
        __syncthreads();

        short8_t af[4], bf[4];
#pragma unroll
        for (int m = 0; m < 4; m++) {
            int rr = wm * 64 + m * 16 + l15;
            af[m] = *(const short8_a*)&As[rr * 40 + l4 * 8];
        }
#pragma unroll
        for (int n = 0; n < 4; n++) {
            int rr = wn * 64 + n * 16 + l15;
            bf[n] = *(const short8_a*)&Bs[rr * 40 + l4 * 8];
        }
#pragma unroll
        for (int m = 0; m < 4; m++)
#pragma unroll
            for (int n = 0; n < 4; n++)
                acc[m][n] = __builtin_amdgcn_mfma_f32_16x16x32_bf16(af[m], bf[n], acc[m][n], 0, 0, 0);
    }

    // epilogue: C/D layout col = lane&15, row = (lane>>4)*4 + i
#pragma unroll
    for (int n = 0; n < 4; n++) {
        int col = n0 + wn * 64 + n * 16 + l15;
        float bv = bias[col];
#pragma unroll
        for (int m = 0; m < 4; m++) {
#pragma unroll
            for (int i = 0; i < 4; i++) {
                int row = m0 + wm * 64 + m * 16 + l4 * 4 + i;
                float v = acc[m][n][i] + bv;
                if (MODE == 0) v *= 0.125f;  // D^-0.5
                if (MODE == 3) {
                    ((float*)out)[row * 1024 + col] = v;
                } else {
                    int b = row & 1, t = row >> 1;
                    int h = col >> 6, d = col & 63;
                    short* o = (short*)out;
                    if (MODE == 2)
                        o[((b * 16 + h) * 64 + d) * 2048 + t] = f2bf(v);
                    else
                        o[((b * 16 + h) * 2048 + t) * 64 + d] = f2bf(v);
                }
            }
        }
    }
}

// ---------------- flash attention ----------------
// Q,K: [B*H][T][64] bf16 (Q pre-scaled). Vt: [B*H][64][T] bf16.
// out attn: [T*B][1024] bf16 (row = t*B+b, col = h*64+d)
__global__ __launch_bounds__(256) void flash_attn(const short* __restrict__ Q,
                                                  const short* __restrict__ K,
                                                  const short* __restrict__ Vt,
                                                  short* __restrict__ O) {
    __shared__ short Ks[32 * 64];      // XOR-swizzled 16B chunks, 2-way conflict
    __shared__ short Vs[64 * 40];      // padded rows (80B)
    __shared__ short Ps[4 * 32 * 40];  // per-wave P tile, padded rows

    const int tid = threadIdx.x, l = tid & 63, w = tid >> 6;
    const int l15 = l & 15, l4 = l >> 4;
    const int qt = blockIdx.x, bh = blockIdx.y;
    const int b = bh >> 4, hh = bh & 15;
    const int q0 = qt * 128;

    const short* Qp = Q + bh * (T_DIM * 64);
    const short* Kp = K + bh * (T_DIM * 64);
    const short* Vp = Vt + bh * (64 * T_DIM);

    // Q fragments held in registers for the whole loop
    short8_t qf[2][2];
#pragma unroll
    for (int qq = 0; qq < 2; qq++)
#pragma unroll
        for (int h = 0; h < 2; h++)
            qf[qq][h] = *(const short8_a*)&Qp[(q0 + w * 32 + qq * 16 + l15) * 64 + h * 32 + l4 * 8];

    f32x4 oacc[2][4];
#pragma unroll
    for (int qq = 0; qq < 2; qq++)
#pragma unroll
        for (int df = 0; df < 4; df++) {
            f32x4 z = {0.f, 0.f, 0.f, 0.f};
            oacc[qq][df] = z;
        }
    float mrow[2][4], lrow[2][4];
#pragma unroll
    for (int qq = 0; qq < 2; qq++)
#pragma unroll
        for (int i = 0; i < 4; i++) {
            mrow[qq][i] = -1e30f;
            lrow[qq][i] = 0.f;
        }

    short* myP = &Ps[w * 32 * 40];

    for (int s0 = 0; s0 < T_DIM; s0 += 32) {
        __syncthreads();
        {
            // stage K tile: 32 rows x 64 (contiguous 2048 shorts), XOR-swizzle chunks
            int row = tid >> 3, c8 = tid & 7;
            *(short8_a*)&Ks[row * 64 + (c8 ^ (row & 7)) * 8] =
                *(const short8_a*)&Kp[s0 * 64 + tid * 8];
            // stage Vt tile: 64 rows x 32, padded rows (b64 writes: 80B rows are 8B-aligned)
            int vr = tid >> 2, vc = tid & 3;
            short8_a vv = *(const short8_a*)&Vp[vr * 2048 + s0 + vc * 8];
            short4_a lo = __builtin_shufflevector(vv, vv, 0, 1, 2, 3);
            short4_a hi = __builtin_shufflevector(vv, vv, 4, 5, 6, 7);
            *(short4_a*)&Vs[vr * 40 + vc * 8] = lo;
            *(short4_a*)&Vs[vr * 40 + vc * 8 + 4] = hi;
        }
        __syncthreads();

        // S = Q K^T  (per wave: 32q x 32s)
        f32x4 s[2][2];
#pragma unroll
        for (int sf = 0; sf < 2; sf++) {
            int rr = sf * 16 + l15;
            short8_t k0f = *(const short8_a*)&Ks[rr * 64 + ((l4) ^ (rr & 7)) * 8];
            short8_t k1f = *(const short8_a*)&Ks[rr * 64 + ((4 + l4) ^ (rr & 7)) * 8];
#pragma unroll
            for (int qq = 0; qq < 2; qq++) {
                f32x4 z = {0.f, 0.f, 0.f, 0.f};
                z = __builtin_amdgcn_mfma_f32_16x16x32_bf16(qf[qq][0], k0f, z, 0, 0, 0);
                z = __builtin_amdgcn_mfma_f32_16x16x32_bf16(qf[qq][1], k1f, z, 0, 0, 0);
                s[qq][sf] = z;
            }
        }

        // online softmax (rows owned by lanes sharing l>>4; reduce across lane&15 group)
#pragma unroll
        for (int qq = 0; qq < 2; qq++) {
#pragma unroll
            for (int i = 0; i < 4; i++) {
                float lm = fmaxf(s[qq][0][i], s[qq][1][i]);
                lm = fmaxf(lm, __shfl_xor(lm, 1));
                lm = fmaxf(lm, __shfl_xor(lm, 2));
                lm = fmaxf(lm, __shfl_xor(lm, 4));
                lm = fmaxf(lm, __shfl_xor(lm, 8));
                float mn = fmaxf(mrow[qq][i], lm);
                float sc = __expf(mrow[qq][i] - mn);
                mrow[qq][i] = mn;
                float p0 = __expf(s[qq][0][i] - mn);
                float p1 = __expf(s[qq][1][i] - mn);
                float ps = p0 + p1;
                ps += __shfl_xor(ps, 1);
                ps += __shfl_xor(ps, 2);
                ps += __shfl_xor(ps, 4);
                ps += __shfl_xor(ps, 8);
                lrow[qq][i] = lrow[qq][i] * sc + ps;
                int prow = qq * 16 + l4 * 4 + i;
                myP[prow * 40 + l15] = f2bf(p0);
                myP[prow * 40 + 16 + l15] = f2bf(p1);
#pragma unroll
                for (int df = 0; df < 4; df++) oacc[qq][df][i] *= sc;
            }
        }

        // PV: O += P[32x32] * V[32x64]   (Vt is [d][s] -> NT form)
        short8_t vfr[4];
#pragma unroll
        for (int df = 0; df < 4; df++)
            vfr[df] = *(const short8_a*)&Vs[(df * 16 + l15) * 40 + l4 * 8];
#pragma unroll
        for (int qq = 0; qq < 2; qq++) {
            short8_t pf = *(const short8_a*)&myP[(qq * 16 + l15) * 40 + l4 * 8];
#pragma unroll
            for (int df = 0; df < 4; df++)
                oacc[qq][df] = __builtin_amdgcn_mfma_f32_16x16x32_bf16(pf, vfr[df], oacc[qq][df], 0, 0, 0);
        }
    }

    // epilogue
#pragma unroll
    for (int qq = 0; qq < 2; qq++) {
#pragma unroll
        for (int df = 0; df < 4; df++) {
#pragma unroll
            for (int i = 0; i < 4; i++) {
                int t = q0 + w * 32 + qq * 16 + l4 * 4 + i;
                int d = df * 16 + l15;
                float v = oacc[qq][df][i] / lrow[qq][i];
                O[(t * 2 + b) * 1024 + hh * 64 + d] = f2bf(v);
            }
        }
    }
}

extern "C" void kernel_launch(void* const* d_in, const int* in_sizes, int n_in,
                              void* d_out, int out_size, void* d_ws, size_t ws_size,
                              hipStream_t stream) {
    const float* query = (const float*)d_in[0];
    const float* Wq = (const float*)d_in[1];
    const float* bq = (const float*)d_in[2];
    const float* Wk = (const float*)d_in[3];
    const float* bk = (const float*)d_in[4];
    const float* Wv = (const float*)d_in[5];
    const float* bv = (const float*)d_in[6];
    const float* Wo = (const float*)d_in[7];
    const float* bo = (const float*)d_in[8];

    // ws layout (shorts). Total = 20,971,520 shorts = 40 MB
    short* Xbf = (short*)d_ws;        // 4096x1024 bf16 query  (8 MB) -- reused as attn out
    short* Wqb = Xbf + 4194304;       // 2 MB each
    short* Wkb = Wqb + 1048576;
    short* Wvb = Wkb + 1048576;
    short* Wob = Wvb + 1048576;
    short* Qb = Wob + 1048576;        // [B,H,T,D] 8 MB
    short* Kb = Qb + 4194304;         // [B,H,T,D] 8 MB
    short* Vtb = Kb + 4194304;        // [B,H,D,T] 8 MB
    short* attnb = Xbf;               // alias: Xbf dead after V projection

    cvt_kernel<<<2048, 256, 0, stream>>>(query, Xbf, 4194304);
    cvt_kernel<<<512, 256, 0, stream>>>(Wq, Wqb, 1048576);
    cvt_kernel<<<512, 256, 0, stream>>>(Wk, Wkb, 1048576);
    cvt_kernel<<<512, 256, 0, stream>>>(Wv, Wvb, 1048576);
    cvt_kernel<<<512, 256, 0, stream>>>(Wo, Wob, 1048576);

    dim3 ggrid(8, 32);
    gemm_proj<0><<<ggrid, 256, 0, stream>>>(Xbf, Wqb, bq, Qb);
    gemm_proj<1><<<ggrid, 256, 0, stream>>>(Xbf, Wkb, bk, Kb);
    gemm_proj<2><<<ggrid, 256, 0, stream>>>(Xbf, Wvb, bv, Vtb);

    flash_attn<<<dim3(16, 32), 256, 0, stream>>>(Qb, Kb, Vtb, attnb);

    gemm_proj<3><<<ggrid, 256, 0, stream>>>(attnb, Wob, bo, (void*)d_out);
}

// Round 2
// 183.421 us; speedup vs baseline: 1.6371x; 1.6371x over previous
//
#include <hip/hip_runtime.h>
#include <hip/hip_bf16.h>

#define T_DIM 2048

typedef __attribute__((ext_vector_type(8))) short short8_t;
typedef short8_t __attribute__((may_alias)) short8_a;
typedef __attribute__((ext_vector_type(4))) short short4_t;
typedef short4_t __attribute__((may_alias)) short4_a;
typedef __attribute__((ext_vector_type(4))) float f32x4;
typedef __attribute__((ext_vector_type(16))) float f32x16;
typedef __attribute__((ext_vector_type(4))) float float4_t;
typedef float4_t __attribute__((may_alias)) float4_a;
typedef __attribute__((ext_vector_type(4))) unsigned int u32x4;

__device__ __forceinline__ short f2bf(float f) {
    unsigned int u = __builtin_bit_cast(unsigned int, f);
    unsigned int r = (u + 0x7fffu + ((u >> 16) & 1u)) >> 16;
    return (short)r;
}

// ---------------- fp32 -> bf16 cast ----------------
__global__ __launch_bounds__(256) void cvt_kernel(const float* __restrict__ in,
                                                  short* __restrict__ out, int n) {
    int i = (blockIdx.x * 256 + threadIdx.x) * 8;
    if (i >= n) return;
    float4_a a = *(const float4_a*)(in + i);
    float4_a b = *(const float4_a*)(in + i + 4);
    short8_a r;
    r[0] = f2bf(a[0]); r[1] = f2bf(a[1]); r[2] = f2bf(a[2]); r[3] = f2bf(a[3]);
    r[4] = f2bf(b[0]); r[5] = f2bf(b[1]); r[6] = f2bf(b[2]); r[7] = f2bf(b[3]);
    *(short8_a*)(out + i) = r;
}

// 4 weight matrices (each 1M elems) in one launch
__global__ __launch_bounds__(256) void cvt_w4(const float* __restrict__ w0, const float* __restrict__ w1,
                                              const float* __restrict__ w2, const float* __restrict__ w3,
                                              short* __restrict__ o0, short* __restrict__ o1,
                                              short* __restrict__ o2, short* __restrict__ o3) {
    const float* in; short* out;
    switch (blockIdx.y) {
        case 0: in = w0; out = o0; break;
        case 1: in = w1; out = o1; break;
        case 2: in = w2; out = o2; break;
        default: in = w3; out = o3; break;
    }
    int i = (blockIdx.x * 256 + threadIdx.x) * 8;
    float4_a a = *(const float4_a*)(in + i);
    float4_a b = *(const float4_a*)(in + i + 4);
    short8_a r;
    r[0] = f2bf(a[0]); r[1] = f2bf(a[1]); r[2] = f2bf(a[2]); r[3] = f2bf(a[3]);
    r[4] = f2bf(b[0]); r[5] = f2bf(b[1]); r[6] = f2bf(b[2]); r[7] = f2bf(b[3]);
    *(short8_a*)(out + i) = r;
}

// ---------------- projection GEMM ----------------
// C[m,n] = sum_k A[m,k] * W[n,k]  (NT form). BM=128, BN=64, BK=32 -> 512 blocks (2/CU).
// MODE 0: Q -> [B,H,T,D] bf16, (acc+bias)*0.125*log2(e)   (exp2 domain for flash)
// MODE 1: K -> [B,H,T,D] bf16
// MODE 2: V -> [B,H,D,T] bf16 (transposed store)
// MODE 3: O -> [T,B,E] fp32
template <int MODE>
__global__ __launch_bounds__(256) void gemm_proj(const short* __restrict__ A,
                                                 const short* __restrict__ W,
                                                 const float* __restrict__ bias,
                                                 void* __restrict__ out) {
    __shared__ short As[128 * 40];  // rows padded to 40 shorts (80B): 2-way conflict = free
    __shared__ short Bs[64 * 40];

    const int tid = threadIdx.x;
    const int l = tid & 63, w = tid >> 6;
    const int wm = w >> 1, wn = w & 1;              // wave tile 64x32
    const int m0 = blockIdx.y * 128, n0 = blockIdx.x * 64;
    const int l15 = l & 15, l4 = l >> 4;

    f32x4 acc[4][2];
#pragma unroll
    for (int i = 0; i < 4; i++)
#pragma unroll
        for (int j = 0; j < 2; j++) {
            f32x4 z = {0.f, 0.f, 0.f, 0.f};
            acc[i][j] = z;
        }

    for (int k0 = 0; k0 < 1024; k0 += 32) {
        __syncthreads();
#pragma unroll
        for (int r = 0; r < 2; r++) {
            int idx = tid + r * 256;
            int row = idx >> 2, ch = idx & 3;
            *(short8_a*)&As[row * 40 + ch * 8] =
                *(const short8_a*)&A[(m0 + row) * 1024 + k0 + ch * 8];
        }
        {
            int row = tid >> 2, ch = tid & 3;
            *(short8_a*)&Bs[row * 40 + ch * 8] =
                *(const short8_a*)&W[(n0 + row) * 1024 + k0 + ch * 8];
        }
        __syncthreads();

        short8_t af[4], bf[2];
#pragma unroll
        for (int m = 0; m < 4; m++)
            af[m] = *(const short8_a*)&As[(wm * 64 + m * 16 + l15) * 40 + l4 * 8];
#pragma unroll
        for (int n = 0; n < 2; n++)
            bf[n] = *(const short8_a*)&Bs[(wn * 32 + n * 16 + l15) * 40 + l4 * 8];
#pragma unroll
        for (int m = 0; m < 4; m++)
#pragma unroll
            for (int n = 0; n < 2; n++)
                acc[m][n] = __builtin_amdgcn_mfma_f32_16x16x32_bf16(af[m], bf[n], acc[m][n], 0, 0, 0);
    }

    // epilogue: C/D layout col = lane&15, row = (lane>>4)*4 + i
#pragma unroll
    for (int n = 0; n < 2; n++) {
        int col = n0 + wn * 32 + n * 16 + l15;
        float bv = bias[col];
#pragma unroll
        for (int m = 0; m < 4; m++) {
#pragma unroll
            for (int i = 0; i < 4; i++) {
                int row = m0 + wm * 64 + m * 16 + l4 * 4 + i;
                float v = acc[m][n][i] + bv;
                if (MODE == 0) v *= 0.18033688011112042f;  // 0.125 * log2(e)
                if (MODE == 3) {
                    ((float*)out)[row * 1024 + col] = v;
                } else {
                    int b = row & 1, t = row >> 1;
                    int h = col >> 6, d = col & 63;
                    short* o = (short*)out;
                    if (MODE == 2)
                        o[((b * 16 + h) * 64 + d) * 2048 + t] = f2bf(v);
                    else
                        o[((b * 16 + h) * 2048 + t) * 64 + d] = f2bf(v);
                }
            }
        }
    }
}

// ---------------- flash attention (swapped-QKT, 32x32x16, KVBLK=64) ----------------
// Q,K: [B*H][T][64] bf16 (Q pre-scaled by 0.125*log2e). Vt: [B*H][64][T] bf16.
// out: [T*B][1024] bf16. 4 waves x 32 q-rows = 128 q per block.
__global__ __launch_bounds__(256) void flash_attn(const short* __restrict__ Q,
                                                  const short* __restrict__ K,
                                                  const short* __restrict__ Vt,
                                                  short* __restrict__ O) {
    __shared__ short Ks[64 * 64];  // [row][chunk slot = ch ^ (row&7)], chunk = 8 shorts (16B)
    __shared__ short Vs[64 * 64];

    const int tid = threadIdx.x, l = tid & 63, w = tid >> 6;
    const int l31 = l & 31, hi = l >> 5;
    const int e = l31 & 7;
    const int bh = blockIdx.y;
    const int b = bh >> 4, hh = bh & 15;
    const int qrow = blockIdx.x * 128 + w * 32 + l31;

    const short* Qp = Q + bh * (T_DIM * 64);
    const short* Kp = K + bh * (T_DIM * 64);
    const short* Vp = Vt + bh * (64 * T_DIM);

    // Q B-frags: B[d = c*16 + hi*8 + j][q = l31]
    short8_t qf[4];
#pragma unroll
    for (int c = 0; c < 4; c++)
        qf[c] = *(const short8_a*)&Qp[qrow * 64 + c * 16 + hi * 8];

    f32x16 oacc[2];
#pragma unroll
    for (int dd = 0; dd < 2; dd++)
#pragma unroll
        for (int i = 0; i < 16; i++) oacc[dd][i] = 0.f;
    float mrow = -1e30f, lsum = 0.f;

    // staging: 512 chunks (64 rows x 8), 2 per thread
    const int srow0 = tid >> 3, sch0 = tid & 7;
    const int srow1 = (tid + 256) >> 3, sch1 = tid & 7;

    short8_t kpre[2], vpre[2];
    kpre[0] = *(const short8_a*)&Kp[srow0 * 64 + sch0 * 8];
    kpre[1] = *(const short8_a*)&Kp[srow1 * 64 + sch1 * 8];
    vpre[0] = *(const short8_a*)&Vp[srow0 * 2048 + sch0 * 8];
    vpre[1] = *(const short8_a*)&Vp[srow1 * 2048 + sch1 * 8];

    for (int it = 0; it < 32; ++it) {
        __syncthreads();  // LDS free
        *(short8_a*)&Ks[srow0 * 64 + (sch0 ^ (srow0 & 7)) * 8] = kpre[0];
        *(short8_a*)&Ks[srow1 * 64 + (sch1 ^ (srow1 & 7)) * 8] = kpre[1];
        *(short8_a*)&Vs[srow0 * 64 + (sch0 ^ (srow0 & 7)) * 8] = vpre[0];
        *(short8_a*)&Vs[srow1 * 64 + (sch1 ^ (srow1 & 7)) * 8] = vpre[1];
        __syncthreads();  // LDS ready

        if (it + 1 < 32) {  // T14: issue next tile's loads; land during compute
            int s0 = (it + 1) * 64;
            kpre[0] = *(const short8_a*)&Kp[(s0 + srow0) * 64 + sch0 * 8];
            kpre[1] = *(const short8_a*)&Kp[(s0 + srow1) * 64 + sch1 * 8];
            vpre[0] = *(const short8_a*)&Vp[srow0 * 2048 + s0 + sch0 * 8];
            vpre[1] = *(const short8_a*)&Vp[srow1 * 2048 + s0 + sch1 * 8];
        }

        // ---- QK^T (swapped): St[k][q], lane holds q=l31 col, k in-register ----
        f32x16 st[2];
#pragma unroll
        for (int r = 0; r < 2; r++) {
#pragma unroll
            for (int i = 0; i < 16; i++) st[r][i] = 0.f;
#pragma unroll
            for (int c = 0; c < 4; c++) {
                short8_t kf = *(const short8_a*)&Ks[(r * 32 + l31) * 64 + ((2 * c + hi) ^ e) * 8];
                st[r] = __builtin_amdgcn_mfma_f32_32x32x16_bf16(kf, qf[c], st[r], 0, 0, 0);
            }
        }

        // ---- online softmax: 31 in-lane fmax + 1 shuffle ----
        float pmax = st[0][0];
#pragma unroll
        for (int i = 1; i < 16; i++) pmax = fmaxf(pmax, st[0][i]);
#pragma unroll
        for (int i = 0; i < 16; i++) pmax = fmaxf(pmax, st[1][i]);
        pmax = fmaxf(pmax, __shfl_xor(pmax, 32));
        float mn = fmaxf(mrow, pmax);
        float sc = exp2f(mrow - mn);
        mrow = mn;
        float ps = 0.f;
#pragma unroll
        for (int r = 0; r < 2; r++)
#pragma unroll
            for (int i = 0; i < 16; i++) {
                float p = exp2f(st[r][i] - mn);
                st[r][i] = p;
                ps += p;
            }
        ps += __shfl_xor(ps, 32);
        lsum = lsum * sc + ps;
#pragma unroll
        for (int dd = 0; dd < 2; dd++)
#pragma unroll
            for (int i = 0; i < 16; i++) oacc[dd][i] *= sc;

        // ---- P pack (cvt_pk) + permlane32_swap -> PV B-frags, all in-register ----
        // After swap(pk[4cc],pk[4cc+2]) & swap(pk[4cc+1],pk[4cc+3]):
        //   {a',a2',b',b2'} gives hi=0 lanes k = 16cc+{0..7}, hi=1 lanes k = 16cc+{8..15},
        //   both naturally ordered -> A-frag (Vt) reads are contiguous 16B.
#pragma unroll
        for (int r = 0; r < 2; r++) {
            unsigned pk8[8];
#pragma unroll
            for (int u = 0; u < 8; u++) {
                unsigned t;
                asm("v_cvt_pk_bf16_f32 %0, %1, %2" : "=v"(t) : "v"(st[r][2 * u]), "v"(st[r][2 * u + 1]));
                pk8[u] = t;
            }
#pragma unroll
            for (int cc = 0; cc < 2; cc++) {
                unsigned A0 = pk8[4 * cc + 0], B0 = pk8[4 * cc + 2];
                unsigned A1 = pk8[4 * cc + 1], B1 = pk8[4 * cc + 3];
                asm("v_permlane32_swap_b32 %0, %1" : "+v"(A0), "+v"(B0));
                asm("v_permlane32_swap_b32 %0, %1" : "+v"(A1), "+v"(B1));
                u32x4 pu = {A0, A1, B0, B1};
                short8_t pf = __builtin_bit_cast(short8_t, pu);
#pragma unroll
                for (int dd = 0; dd < 2; dd++) {
                    short8_t vf = *(const short8_a*)&Vs[(dd * 32 + l31) * 64 +
                                                        ((4 * r + 2 * cc + hi) ^ e) * 8];
                    oacc[dd] = __builtin_amdgcn_mfma_f32_32x32x16_bf16(vf, pf, oacc[dd], 0, 0, 0);
                }
            }
        }
    }

    // ---- epilogue: lane holds O^T[d][q=l31], d = (reg&3)+8*(reg>>2)+4*hi+32*dd ----
    float rl = 1.0f / lsum;
#pragma unroll
    for (int dd = 0; dd < 2; dd++)
#pragma unroll
        for (int g = 0; g < 4; g++) {
            short4_t o4;
#pragma unroll
            for (int i = 0; i < 4; i++) o4[i] = f2bf(oacc[dd][4 * g + i] * rl);
            *(short4_a*)&O[(qrow * 2 + b) * 1024 + hh * 64 + dd * 32 + g * 8 + hi * 4] = o4;
        }
}

extern "C" void kernel_launch(void* const* d_in, const int* in_sizes, int n_in,
                              void* d_out, int out_size, void* d_ws, size_t ws_size,
                              hipStream_t stream) {
    const float* query = (const float*)d_in[0];
    const float* Wq = (const float*)d_in[1];
    const float* bq = (const float*)d_in[2];
    const float* Wk = (const float*)d_in[3];
    const float* bk = (const float*)d_in[4];
    const float* Wv = (const float*)d_in[5];
    const float* bv = (const float*)d_in[6];
    const float* Wo = (const float*)d_in[7];
    const float* bo = (const float*)d_in[8];

    // ws layout (shorts). Total = 20,971,520 shorts = 40 MB
    short* Xbf = (short*)d_ws;        // 4096x1024 bf16 query (8 MB) -- reused as attn out
    short* Wqb = Xbf + 4194304;
    short* Wkb = Wqb + 1048576;
    short* Wvb = Wkb + 1048576;
    short* Wob = Wvb + 1048576;
    short* Qb = Wob + 1048576;        // [B,H,T,D] 8 MB
    short* Kb = Qb + 4194304;         // [B,H,T,D] 8 MB
    short* Vtb = Kb + 4194304;        // [B,H,D,T] 8 MB
    short* attnb = Xbf;               // alias: Xbf dead after V projection

    cvt_kernel<<<2048, 256, 0, stream>>>(query, Xbf, 4194304);
    cvt_w4<<<dim3(512, 4), 256, 0, stream>>>(Wq, Wk, Wv, Wo, Wqb, Wkb, Wvb, Wob);

    dim3 ggrid(16, 32);  // BN=64 x BM=128 -> 512 blocks (2/CU)
    gemm_proj<0><<<ggrid, 256, 0, stream>>>(Xbf, Wqb, bq, Qb);
    gemm_proj<1><<<ggrid, 256, 0, stream>>>(Xbf, Wkb, bk, Kb);
    gemm_proj<2><<<ggrid, 256, 0, stream>>>(Xbf, Wvb, bv, Vtb);

    flash_attn<<<dim3(16, 32), 256, 0, stream>>>(Qb, Kb, Vtb, attnb);

    gemm_proj<3><<<ggrid, 256, 0, stream>>>(attnb, Wob, bo, (void*)d_out);
}

// Round 3
// 153.410 us; speedup vs baseline: 1.9574x; 1.1956x over previous
//
#include <hip/hip_runtime.h>
#include <hip/hip_bf16.h>

#define T_DIM 2048

typedef __attribute__((ext_vector_type(8))) short short8_t;
typedef short8_t __attribute__((may_alias)) short8_a;
typedef __attribute__((ext_vector_type(4))) short short4_t;
typedef short4_t __attribute__((may_alias)) short4_a;
typedef __attribute__((ext_vector_type(4))) float f32x4;
typedef __attribute__((ext_vector_type(16))) float f32x16;
typedef __attribute__((ext_vector_type(4))) float float4_t;
typedef float4_t __attribute__((may_alias)) float4_a;
typedef __attribute__((ext_vector_type(4))) unsigned int u32x4;

__device__ __forceinline__ short f2bf(float f) {
    unsigned int u = __builtin_bit_cast(unsigned int, f);
    unsigned int r = (u + 0x7fffu + ((u >> 16) & 1u)) >> 16;
    return (short)r;
}

// ---------------- fp32 -> bf16 cast ----------------
__global__ __launch_bounds__(256) void cvt_kernel(const float* __restrict__ in,
                                                  short* __restrict__ out, int n) {
    int i = (blockIdx.x * 256 + threadIdx.x) * 8;
    if (i >= n) return;
    float4_a a = *(const float4_a*)(in + i);
    float4_a b = *(const float4_a*)(in + i + 4);
    short8_a r;
    r[0] = f2bf(a[0]); r[1] = f2bf(a[1]); r[2] = f2bf(a[2]); r[3] = f2bf(a[3]);
    r[4] = f2bf(b[0]); r[5] = f2bf(b[1]); r[6] = f2bf(b[2]); r[7] = f2bf(b[3]);
    *(short8_a*)(out + i) = r;
}

// 4 weight matrices (each 1M elems) in one launch
__global__ __launch_bounds__(256) void cvt_w4(const float* __restrict__ w0, const float* __restrict__ w1,
                                              const float* __restrict__ w2, const float* __restrict__ w3,
                                              short* __restrict__ o0, short* __restrict__ o1,
                                              short* __restrict__ o2, short* __restrict__ o3) {
    const float* in; short* out;
    switch (blockIdx.y) {
        case 0: in = w0; out = o0; break;
        case 1: in = w1; out = o1; break;
        case 2: in = w2; out = o2; break;
        default: in = w3; out = o3; break;
    }
    int i = (blockIdx.x * 256 + threadIdx.x) * 8;
    float4_a a = *(const float4_a*)(in + i);
    float4_a b = *(const float4_a*)(in + i + 4);
    short8_a r;
    r[0] = f2bf(a[0]); r[1] = f2bf(a[1]); r[2] = f2bf(a[2]); r[3] = f2bf(a[3]);
    r[4] = f2bf(b[0]); r[5] = f2bf(b[1]); r[6] = f2bf(b[2]); r[7] = f2bf(b[3]);
    *(short8_a*)(out + i) = r;
}

// ---------------- projection GEMM (double-buffered LDS, 1 barrier/k-step) ----------------
// C[m,n] = sum_k A[m,k] * W[n,k]  (NT form). BM=128, BN=64, BK=32.
// MODE 4: fused QKV (W = [3072][1024] = Wq|Wk|Wv rows). per-block proj = n0>>10:
//   proj 0: Q -> [B,H,T,D] bf16, (acc+bias)*0.125*log2(e)
//   proj 1: K -> [B,H,T,D] bf16
//   proj 2: V -> [B,H,D,T] bf16 (transposed store)
// MODE 3: O -> [T,B,E] fp32
template <int MODE>
__global__ __launch_bounds__(256) void gemm_nt(const short* __restrict__ A,
                                               const short* __restrict__ W,
                                               const float* __restrict__ b0,
                                               const float* __restrict__ b1,
                                               const float* __restrict__ b2,
                                               short* __restrict__ o0,
                                               short* __restrict__ o1,
                                               short* __restrict__ o2,
                                               float* __restrict__ of) {
    __shared__ short As[2][128 * 40];  // rows padded to 40 shorts: 2-way conflict = free
    __shared__ short Bs[2][64 * 40];

    const int tid = threadIdx.x;
    const int l = tid & 63, w = tid >> 6;
    const int wm = w >> 1, wn = w & 1;  // wave tile 64x32
    const int m0 = blockIdx.y * 128, n0 = blockIdx.x * 64;
    const int l15 = l & 15, l4 = l >> 4;

    const int ar0 = tid >> 2, ac = tid & 3, ar1 = ar0 + 64;
    const int br = tid >> 2;

    f32x4 acc[4][2];
#pragma unroll
    for (int i = 0; i < 4; i++)
#pragma unroll
        for (int j = 0; j < 2; j++) {
            f32x4 z = {0.f, 0.f, 0.f, 0.f};
            acc[i][j] = z;
        }

    short8_t apre0, apre1, bpre;
    apre0 = *(const short8_a*)&A[(m0 + ar0) * 1024 + ac * 8];
    apre1 = *(const short8_a*)&A[(m0 + ar1) * 1024 + ac * 8];
    bpre = *(const short8_a*)&W[(n0 + br) * 1024 + ac * 8];
    *(short8_a*)&As[0][ar0 * 40 + ac * 8] = apre0;
    *(short8_a*)&As[0][ar1 * 40 + ac * 8] = apre1;
    *(short8_a*)&Bs[0][br * 40 + ac * 8] = bpre;

    auto step = [&](const short* as, const short* bs, short* an, short* bn, int k0) {
        __syncthreads();
        int kn = k0 + 32;
        if (kn < 1024) {
            apre0 = *(const short8_a*)&A[(m0 + ar0) * 1024 + kn + ac * 8];
            apre1 = *(const short8_a*)&A[(m0 + ar1) * 1024 + kn + ac * 8];
            bpre = *(const short8_a*)&W[(n0 + br) * 1024 + kn + ac * 8];
        }
        short8_t af[4], bf2[2];
#pragma unroll
        for (int m = 0; m < 4; m++)
            af[m] = *(const short8_a*)&as[(wm * 64 + m * 16 + l15) * 40 + l4 * 8];
#pragma unroll
        for (int n = 0; n < 2; n++)
            bf2[n] = *(const short8_a*)&bs[(wn * 32 + n * 16 + l15) * 40 + l4 * 8];
#pragma unroll
        for (int m = 0; m < 4; m++)
#pragma unroll
            for (int n = 0; n < 2; n++)
                acc[m][n] = __builtin_amdgcn_mfma_f32_16x16x32_bf16(af[m], bf2[n], acc[m][n], 0, 0, 0);
        if (kn < 1024) {
            *(short8_a*)&an[ar0 * 40 + ac * 8] = apre0;
            *(short8_a*)&an[ar1 * 40 + ac * 8] = apre1;
            *(short8_a*)&bn[br * 40 + ac * 8] = bpre;
        }
    };

    for (int k0 = 0; k0 < 1024; k0 += 64) {
        step(As[0], Bs[0], As[1], Bs[1], k0);
        step(As[1], Bs[1], As[0], Bs[0], k0 + 32);
    }

    // epilogue: C/D layout col = lane&15, row = (lane>>4)*4 + i
    if (MODE == 3) {
#pragma unroll
        for (int n = 0; n < 2; n++) {
            int col = n0 + wn * 32 + n * 16 + l15;
            float bv = b0[col];
#pragma unroll
            for (int m = 0; m < 4; m++)
#pragma unroll
                for (int i = 0; i < 4; i++) {
                    int row = m0 + wm * 64 + m * 16 + l4 * 4 + i;
                    of[row * 1024 + col] = acc[m][n][i] + bv;
                }
        }
    } else {
        const int proj = n0 >> 10;  // uniform per block
        const float* bias = proj == 0 ? b0 : (proj == 1 ? b1 : b2);
        short* outp = proj == 0 ? o0 : (proj == 1 ? o1 : o2);
#pragma unroll
        for (int n = 0; n < 2; n++) {
            int cw = (n0 + wn * 32 + n * 16 + l15) & 1023;
            float bv = bias[cw];
            int h = cw >> 6, d = cw & 63;
#pragma unroll
            for (int m = 0; m < 4; m++)
#pragma unroll
                for (int i = 0; i < 4; i++) {
                    int row = m0 + wm * 64 + m * 16 + l4 * 4 + i;
                    float v = acc[m][n][i] + bv;
                    if (proj == 0) v *= 0.18033688011112042f;  // 0.125 * log2(e)
                    int bb = row & 1, t = row >> 1;
                    if (proj == 2)
                        outp[((bb * 16 + h) * 64 + d) * 2048 + t] = f2bf(v);
                    else
                        outp[((bb * 16 + h) * 2048 + t) * 64 + d] = f2bf(v);
                }
        }
    }
}

// ---------------- flash attention (swapped-QKT, 32x32x16, KVBLK=64, LDS dbuf) ----------------
// Q,K: [B*H][T][64] bf16 (Q pre-scaled by 0.125*log2e). Vt: [B*H][64][T] bf16.
// out: [T*B][1024] bf16. 4 waves x 32 q-rows = 128 q per block.
__global__ __launch_bounds__(256) void flash_attn(const short* __restrict__ Q,
                                                  const short* __restrict__ K,
                                                  const short* __restrict__ Vt,
                                                  short* __restrict__ O) {
    __shared__ short Ks[2][64 * 64];  // [row][chunk slot = ch ^ (row&7)], chunk = 8 shorts
    __shared__ short Vs[2][64 * 64];

    const int tid = threadIdx.x, l = tid & 63, w = tid >> 6;
    const int l31 = l & 31, hi = l >> 5;
    const int e = l31 & 7;
    const int bh = blockIdx.y;
    const int b = bh >> 4, hh = bh & 15;
    const int qrow = blockIdx.x * 128 + w * 32 + l31;

    const short* Qp = Q + bh * (T_DIM * 64);
    const short* Kp = K + bh * (T_DIM * 64);
    const short* Vp = Vt + bh * (64 * T_DIM);

    // Q B-frags: B[d = c*16 + hi*8 + j][q = l31]
    short8_t qf[4];
#pragma unroll
    for (int c = 0; c < 4; c++)
        qf[c] = *(const short8_a*)&Qp[qrow * 64 + c * 16 + hi * 8];

    f32x16 oacc[2];
    f32x16 lacc;  // row-sum accumulator via ones-MFMA; only [0] consumed
#pragma unroll
    for (int i = 0; i < 16; i++) { oacc[0][i] = 0.f; oacc[1][i] = 0.f; lacc[i] = 0.f; }
    float mrow = -1e30f;

    short8_t ones;
#pragma unroll
    for (int j = 0; j < 8; j++) ones[j] = (short)0x3F80;  // bf16 1.0

    // staging: 512 chunks (64 rows x 8), 2 per thread
    const int srow0 = tid >> 3, sch = tid & 7;
    const int srow1 = srow0 + 32;
    const int kslot0 = (sch ^ (srow0 & 7)) * 8;
    const int kslot1 = (sch ^ (srow1 & 7)) * 8;

    short8_t kpre[2], vpre[2];
    kpre[0] = *(const short8_a*)&Kp[srow0 * 64 + sch * 8];
    kpre[1] = *(const short8_a*)&Kp[srow1 * 64 + sch * 8];
    vpre[0] = *(const short8_a*)&Vp[srow0 * 2048 + sch * 8];
    vpre[1] = *(const short8_a*)&Vp[srow1 * 2048 + sch * 8];
    *(short8_a*)&Ks[0][srow0 * 64 + kslot0] = kpre[0];
    *(short8_a*)&Ks[0][srow1 * 64 + kslot1] = kpre[1];
    *(short8_a*)&Vs[0][srow0 * 64 + kslot0] = vpre[0];
    *(short8_a*)&Vs[0][srow1 * 64 + kslot1] = vpre[1];

    auto body = [&](const short* kc, const short* vc, short* kn, short* vn, int it) {
        __syncthreads();  // prev iter's reads of (kn,vn) and writes of (kc,vc) done
        if (it + 1 < 32) {  // T14: issue next tile's loads; land during compute
            int s0 = (it + 1) * 64;
            kpre[0] = *(const short8_a*)&Kp[(s0 + srow0) * 64 + sch * 8];
            kpre[1] = *(const short8_a*)&Kp[(s0 + srow1) * 64 + sch * 8];
            vpre[0] = *(const short8_a*)&Vp[srow0 * 2048 + s0 + sch * 8];
            vpre[1] = *(const short8_a*)&Vp[srow1 * 2048 + s0 + sch * 8];
        }

        // ---- QK^T (swapped): St[k][q], lane holds q=l31 col, k in-register ----
        f32x16 st[2];
#pragma unroll
        for (int r = 0; r < 2; r++) {
#pragma unroll
            for (int i = 0; i < 16; i++) st[r][i] = 0.f;
#pragma unroll
            for (int c = 0; c < 4; c++) {
                short8_t kf = *(const short8_a*)&kc[(r * 32 + l31) * 64 + ((2 * c + hi) ^ e) * 8];
                st[r] = __builtin_amdgcn_mfma_f32_32x32x16_bf16(kf, qf[c], st[r], 0, 0, 0);
            }
        }

        // ---- online softmax, defer-max (T13, exp2 domain, THR=8 -> p <= 256) ----
        float pmax = st[0][0];
#pragma unroll
        for (int i = 1; i < 16; i++) pmax = fmaxf(pmax, st[0][i]);
#pragma unroll
        for (int i = 0; i < 16; i++) pmax = fmaxf(pmax, st[1][i]);
        pmax = fmaxf(pmax, __shfl_xor(pmax, 32));
        if (__any(pmax > mrow + 8.f)) {
            float mn = fmaxf(mrow, pmax);
            float sc = exp2f(mrow - mn);
            mrow = mn;
            lacc[0] *= sc;
#pragma unroll
            for (int dd = 0; dd < 2; dd++)
#pragma unroll
                for (int i = 0; i < 16; i++) oacc[dd][i] *= sc;
        }
#pragma unroll
        for (int r = 0; r < 2; r++)
#pragma unroll
            for (int i = 0; i < 16; i++) st[r][i] = exp2f(st[r][i] - mrow);

        // ---- P pack (cvt_pk) + permlane32_swap -> PV B-frags, all in-register ----
#pragma unroll
        for (int r = 0; r < 2; r++) {
            unsigned pk8[8];
#pragma unroll
            for (int u = 0; u < 8; u++) {
                unsigned t;
                asm("v_cvt_pk_bf16_f32 %0, %1, %2" : "=v"(t) : "v"(st[r][2 * u]), "v"(st[r][2 * u + 1]));
                pk8[u] = t;
            }
#pragma unroll
            for (int cc = 0; cc < 2; cc++) {
                unsigned A0 = pk8[4 * cc + 0], B0 = pk8[4 * cc + 2];
                unsigned A1 = pk8[4 * cc + 1], B1 = pk8[4 * cc + 3];
                asm("v_permlane32_swap_b32 %0, %1" : "+v"(A0), "+v"(B0));
                asm("v_permlane32_swap_b32 %0, %1" : "+v"(A1), "+v"(B1));
                u32x4 pu = {A0, A1, B0, B1};
                short8_t pf = __builtin_bit_cast(short8_t, pu);
                // row-sum on the MFMA pipe: all-ones A => every row = sum_k P[k][q]
                lacc = __builtin_amdgcn_mfma_f32_32x32x16_bf16(ones, pf, lacc, 0, 0, 0);
#pragma unroll
                for (int dd = 0; dd < 2; dd++) {
                    short8_t vf = *(const short8_a*)&vc[(dd * 32 + l31) * 64 +
                                                        ((4 * r + 2 * cc + hi) ^ e) * 8];
                    oacc[dd] = __builtin_amdgcn_mfma_f32_32x32x16_bf16(vf, pf, oacc[dd], 0, 0, 0);
                }
            }
        }

        if (it + 1 < 32) {  // write next tile into the other buffer
            *(short8_a*)&kn[srow0 * 64 + kslot0] = kpre[0];
            *(short8_a*)&kn[srow1 * 64 + kslot1] = kpre[1];
            *(short8_a*)&vn[srow0 * 64 + kslot0] = vpre[0];
            *(short8_a*)&vn[srow1 * 64 + kslot1] = vpre[1];
        }
    };

    for (int it = 0; it < 32; it += 2) {
        body(Ks[0], Vs[0], Ks[1], Vs[1], it);
        body(Ks[1], Vs[1], Ks[0], Vs[0], it + 1);
    }

    // ---- epilogue: lane holds O^T[d][q=l31], d = (reg&3)+8*(reg>>2)+4*hi+32*dd ----
    float rl = 1.0f / lacc[0];
#pragma unroll
    for (int dd = 0; dd < 2; dd++)
#pragma unroll
        for (int g = 0; g < 4; g++) {
            short4_t o4;
#pragma unroll
            for (int i = 0; i < 4; i++) o4[i] = f2bf(oacc[dd][4 * g + i] * rl);
            *(short4_a*)&O[(qrow * 2 + b) * 1024 + hh * 64 + dd * 32 + g * 8 + hi * 4] = o4;
        }
}

extern "C" void kernel_launch(void* const* d_in, const int* in_sizes, int n_in,
                              void* d_out, int out_size, void* d_ws, size_t ws_size,
                              hipStream_t stream) {
    const float* query = (const float*)d_in[0];
    const float* Wq = (const float*)d_in[1];
    const float* bq = (const float*)d_in[2];
    const float* Wk = (const float*)d_in[3];
    const float* bk = (const float*)d_in[4];
    const float* Wv = (const float*)d_in[5];
    const float* bv = (const float*)d_in[6];
    const float* Wo = (const float*)d_in[7];
    const float* bo = (const float*)d_in[8];

    // ws layout (shorts). Total = 20,971,520 shorts = 40 MB
    short* Xbf = (short*)d_ws;        // 4096x1024 bf16 query (8 MB) -- reused as attn out
    short* Wqb = Xbf + 4194304;       // Wq|Wk|Wv contiguous = fused [3072][1024]
    short* Wkb = Wqb + 1048576;
    short* Wvb = Wkb + 1048576;
    short* Wob = Wvb + 1048576;
    short* Qb = Wob + 1048576;        // [B,H,T,D] 8 MB
    short* Kb = Qb + 4194304;         // [B,H,T,D] 8 MB
    short* Vtb = Kb + 4194304;        // [B,H,D,T] 8 MB
    short* attnb = Xbf;               // alias: Xbf dead after QKV projection

    cvt_kernel<<<2048, 256, 0, stream>>>(query, Xbf, 4194304);
    cvt_w4<<<dim3(512, 4), 256, 0, stream>>>(Wq, Wk, Wv, Wo, Wqb, Wkb, Wvb, Wob);

    // fused QKV: M=4096, N=3072 -> 1536 blocks (~5-6/CU)
    gemm_nt<4><<<dim3(48, 32), 256, 0, stream>>>(Xbf, Wqb, bq, bk, bv, Qb, Kb, Vtb, nullptr);

    flash_attn<<<dim3(16, 32), 256, 0, stream>>>(Qb, Kb, Vtb, attnb);

    gemm_nt<3><<<dim3(16, 32), 256, 0, stream>>>(attnb, Wob, bo, nullptr, nullptr,
                                                 nullptr, nullptr, nullptr, (float*)d_out);
}

// Round 4
// 136.701 us; speedup vs baseline: 2.1966x; 1.1222x over previous
//
#include <hip/hip_runtime.h>
#include <hip/hip_bf16.h>

#define T_DIM 2048

typedef __attribute__((ext_vector_type(8))) short short8_t;
typedef short8_t __attribute__((may_alias)) short8_a;
typedef __attribute__((ext_vector_type(4))) short short4_t;
typedef short4_t __attribute__((may_alias)) short4_a;
typedef __attribute__((ext_vector_type(4))) float f32x4;
typedef __attribute__((ext_vector_type(16))) float f32x16;
typedef __attribute__((ext_vector_type(4))) float float4_t;
typedef float4_t __attribute__((may_alias)) float4_a;
typedef __attribute__((ext_vector_type(4))) unsigned int u32x4;

__device__ __forceinline__ short f2bf(float f) {
    unsigned int u = __builtin_bit_cast(unsigned int, f);
    unsigned int r = (u + 0x7fffu + ((u >> 16) & 1u)) >> 16;
    return (short)r;
}

// async global->LDS, 16B per lane. lds dst must be wave-uniform base (+ lane*16 implicit).
__device__ __forceinline__ void gl_lds16(const short* g, short* l) {
    __builtin_amdgcn_global_load_lds(
        (const __attribute__((address_space(1))) void*)g,
        (__attribute__((address_space(3))) void*)l, 16, 0, 0);
}

// ---------------- fp32 -> bf16 cast ----------------
__global__ __launch_bounds__(256) void cvt_kernel(const float* __restrict__ in,
                                                  short* __restrict__ out, int n) {
    int i = (blockIdx.x * 256 + threadIdx.x) * 8;
    if (i >= n) return;
    float4_a a = *(const float4_a*)(in + i);
    float4_a b = *(const float4_a*)(in + i + 4);
    short8_a r;
    r[0] = f2bf(a[0]); r[1] = f2bf(a[1]); r[2] = f2bf(a[2]); r[3] = f2bf(a[3]);
    r[4] = f2bf(b[0]); r[5] = f2bf(b[1]); r[6] = f2bf(b[2]); r[7] = f2bf(b[3]);
    *(short8_a*)(out + i) = r;
}

// 4 weight matrices (each 1M elems) in one launch
__global__ __launch_bounds__(256) void cvt_w4(const float* __restrict__ w0, const float* __restrict__ w1,
                                              const float* __restrict__ w2, const float* __restrict__ w3,
                                              short* __restrict__ o0, short* __restrict__ o1,
                                              short* __restrict__ o2, short* __restrict__ o3) {
    const float* in; short* out;
    switch (blockIdx.y) {
        case 0: in = w0; out = o0; break;
        case 1: in = w1; out = o1; break;
        case 2: in = w2; out = o2; break;
        default: in = w3; out = o3; break;
    }
    int i = (blockIdx.x * 256 + threadIdx.x) * 8;
    float4_a a = *(const float4_a*)(in + i);
    float4_a b = *(const float4_a*)(in + i + 4);
    short8_a r;
    r[0] = f2bf(a[0]); r[1] = f2bf(a[1]); r[2] = f2bf(a[2]); r[3] = f2bf(a[3]);
    r[4] = f2bf(b[0]); r[5] = f2bf(b[1]); r[6] = f2bf(b[2]); r[7] = f2bf(b[3]);
    *(short8_a*)(out + i) = r;
}

// ---------------- m97-structure GEMM: global_load_lds + linear LDS, BK=32 ----------------
// C[m,n] = sum_k A[m,k] * W[n,k]  (NT form). 4 waves (2x2), wave tile (BM/2)x(BN/2).
// MODE 4: fused QKV (W = [3072][1024] rows = Wq|Wk|Wv). proj = n0>>10:
//   proj 0: Q -> [B,H,T,D] bf16, (acc+bias)*0.125*log2(e)
//   proj 1: K -> [B,H,T,D] bf16
//   proj 2: V -> [B,H,D,T] bf16 (transposed store)
// MODE 3: O -> [T,B,E] fp32
template <int BM, int BN, int MODE>
__global__ __launch_bounds__(256) void gemm_lds(const short* __restrict__ A,
                                                const short* __restrict__ W,
                                                const float* __restrict__ b0,
                                                const float* __restrict__ b1,
                                                const float* __restrict__ b2,
                                                short* __restrict__ o0,
                                                short* __restrict__ o1,
                                                short* __restrict__ o2,
                                                float* __restrict__ of) {
    constexpr int FM = BM / 32;  // 16x16 frags per wave (M)
    constexpr int FN = BN / 32;
    __shared__ short As[BM * 32];  // linear [row][32] shorts (64B rows)
    __shared__ short Bs[BN * 32];

    const int tid = threadIdx.x;
    const int l = tid & 63, w = tid >> 6;
    const int wm = w >> 1, wn = w & 1;
    const int m0 = blockIdx.y * BM, n0 = blockIdx.x * BN;
    const int l15 = l & 15, l4 = l >> 4;
    const int lr = l >> 2, lc = (l & 3) * 8;  // staging lane: 16 rows x 4 chunks per inst

    f32x4 acc[FM][FN];
#pragma unroll
    for (int i = 0; i < FM; i++)
#pragma unroll
        for (int j = 0; j < FN; j++) {
            f32x4 z = {0.f, 0.f, 0.f, 0.f};
            acc[i][j] = z;
        }

    const short* Ab = A + (m0 + lr) * 1024 + lc;
    const short* Wb = W + (n0 + lr) * 1024 + lc;

    for (int k0 = 0; k0 < 1024; k0 += 32) {
        // stage: issue async loads (dest = wave-uniform LDS base)
#pragma unroll
        for (int j = 0; j < BM / 64; j++) {
            int base = (j * 4 + w) * 16;  // 16 rows per inst
            gl_lds16(Ab + base * 1024 + k0, &As[base * 32]);
        }
#pragma unroll
        for (int j = 0; j < BN / 64; j++) {
            int base = (j * 4 + w) * 16;
            gl_lds16(Wb + base * 1024 + k0, &Bs[base * 32]);
        }
        __syncthreads();  // compiler drains vmcnt(0) before s_barrier

        short8_t af[FM], bf[FN];
#pragma unroll
        for (int m = 0; m < FM; m++)
            af[m] = *(const short8_a*)&As[(wm * (BM / 2) + m * 16 + l15) * 32 + l4 * 8];
#pragma unroll
        for (int n = 0; n < FN; n++)
            bf[n] = *(const short8_a*)&Bs[(wn * (BN / 2) + n * 16 + l15) * 32 + l4 * 8];
#pragma unroll
        for (int m = 0; m < FM; m++)
#pragma unroll
            for (int n = 0; n < FN; n++)
                acc[m][n] = __builtin_amdgcn_mfma_f32_16x16x32_bf16(af[m], bf[n], acc[m][n], 0, 0, 0);
        __syncthreads();  // readers done before next stage overwrites
    }

    // epilogue: C/D layout col = lane&15, row = (lane>>4)*4 + i
    if (MODE == 3) {
#pragma unroll
        for (int n = 0; n < FN; n++) {
            int col = n0 + wn * (BN / 2) + n * 16 + l15;
            float bv = b0[col];
#pragma unroll
            for (int m = 0; m < FM; m++)
#pragma unroll
                for (int i = 0; i < 4; i++) {
                    int row = m0 + wm * (BM / 2) + m * 16 + l4 * 4 + i;
                    of[row * 1024 + col] = acc[m][n][i] + bv;
                }
        }
    } else {
        const int proj = n0 >> 10;  // uniform per block
        const float* bias = proj == 0 ? b0 : (proj == 1 ? b1 : b2);
        short* outp = proj == 0 ? o0 : (proj == 1 ? o1 : o2);
#pragma unroll
        for (int n = 0; n < FN; n++) {
            int cw = (n0 + wn * (BN / 2) + n * 16 + l15) & 1023;
            float bv = bias[cw];
            int h = cw >> 6, d = cw & 63;
#pragma unroll
            for (int m = 0; m < FM; m++)
#pragma unroll
                for (int i = 0; i < 4; i++) {
                    int row = m0 + wm * (BM / 2) + m * 16 + l4 * 4 + i;
                    float v = acc[m][n][i] + bv;
                    if (proj == 0) v *= 0.18033688011112042f;  // 0.125 * log2(e)
                    int bb = row & 1, t = row >> 1;
                    if (proj == 2)
                        outp[((bb * 16 + h) * 64 + d) * 2048 + t] = f2bf(v);
                    else
                        outp[((bb * 16 + h) * 2048 + t) * 64 + d] = f2bf(v);
                }
        }
    }
}

__device__ __forceinline__ float max16(const f32x16 v) {
    // balanced tree of triples -> v_max3 fusion, short dep chain
    float a0 = fmaxf(fmaxf(v[0], v[1]), v[2]);
    float a1 = fmaxf(fmaxf(v[3], v[4]), v[5]);
    float a2 = fmaxf(fmaxf(v[6], v[7]), v[8]);
    float a3 = fmaxf(fmaxf(v[9], v[10]), v[11]);
    float a4 = fmaxf(fmaxf(v[12], v[13]), v[14]);
    float b0 = fmaxf(fmaxf(a0, a1), v[15]);
    float b1 = fmaxf(fmaxf(a2, a3), a4);
    return fmaxf(b0, b1);
}

// ---------------- flash attention (swapped-QKT, 32x32x16, KVBLK=64, LDS dbuf) ----------------
// Q,K: [B*H][T][64] bf16 (Q pre-scaled by 0.125*log2e). Vt: [B*H][64][T] bf16.
// out: [T*B][1024] bf16. 4 waves x 32 q-rows = 128 q per block.
__global__ __launch_bounds__(256) void flash_attn(const short* __restrict__ Q,
                                                  const short* __restrict__ K,
                                                  const short* __restrict__ Vt,
                                                  short* __restrict__ O) {
    __shared__ short Ks[2][64 * 64];  // [row][chunk slot = ch ^ (row&7)], chunk = 8 shorts
    __shared__ short Vs[2][64 * 64];

    const int tid = threadIdx.x, l = tid & 63, w = tid >> 6;
    const int l31 = l & 31, hi = l >> 5;
    const int e = l31 & 7;
    const int bh = blockIdx.y;
    const int b = bh >> 4, hh = bh & 15;
    const int qrow = blockIdx.x * 128 + w * 32 + l31;

    const short* Qp = Q + bh * (T_DIM * 64);
    const short* Kp = K + bh * (T_DIM * 64);
    const short* Vp = Vt + bh * (64 * T_DIM);

    // Q B-frags: B[d = c*16 + hi*8 + j][q = l31]
    short8_t qf[4];
#pragma unroll
    for (int c = 0; c < 4; c++)
        qf[c] = *(const short8_a*)&Qp[qrow * 64 + c * 16 + hi * 8];

    f32x16 oacc[2];
    f32x16 lacc;  // row-sum accumulator via ones-MFMA; only [0] consumed
#pragma unroll
    for (int i = 0; i < 16; i++) { oacc[0][i] = 0.f; oacc[1][i] = 0.f; lacc[i] = 0.f; }
    float mrow = -1e30f;

    short8_t ones;
#pragma unroll
    for (int j = 0; j < 8; j++) ones[j] = (short)0x3F80;  // bf16 1.0

    // staging: 512 chunks (64 rows x 8), 2 per thread
    const int srow0 = tid >> 3, sch = tid & 7;
    const int srow1 = srow0 + 32;
    const int kslot0 = (sch ^ (srow0 & 7)) * 8;
    const int kslot1 = (sch ^ (srow1 & 7)) * 8;

    short8_t kpre[2], vpre[2];
    kpre[0] = *(const short8_a*)&Kp[srow0 * 64 + sch * 8];
    kpre[1] = *(const short8_a*)&Kp[srow1 * 64 + sch * 8];
    vpre[0] = *(const short8_a*)&Vp[srow0 * 2048 + sch * 8];
    vpre[1] = *(const short8_a*)&Vp[srow1 * 2048 + sch * 8];
    *(short8_a*)&Ks[0][srow0 * 64 + kslot0] = kpre[0];
    *(short8_a*)&Ks[0][srow1 * 64 + kslot1] = kpre[1];
    *(short8_a*)&Vs[0][srow0 * 64 + kslot0] = vpre[0];
    *(short8_a*)&Vs[0][srow1 * 64 + kslot1] = vpre[1];

    auto body = [&](const short* kc, const short* vc, short* kn, short* vn, int it) {
        __syncthreads();  // prev iter's reads of (kn,vn) and writes of (kc,vc) done
        if (it + 1 < 32) {  // T14: issue next tile's loads; land during compute
            int s0 = (it + 1) * 64;
            kpre[0] = *(const short8_a*)&Kp[(s0 + srow0) * 64 + sch * 8];
            kpre[1] = *(const short8_a*)&Kp[(s0 + srow1) * 64 + sch * 8];
            vpre[0] = *(const short8_a*)&Vp[srow0 * 2048 + s0 + sch * 8];
            vpre[1] = *(const short8_a*)&Vp[srow1 * 2048 + s0 + sch * 8];
        }

        // ---- QK^T (swapped): St[k][q], lane holds q=l31 col, k in-register ----
        f32x16 st[2];
#pragma unroll
        for (int r = 0; r < 2; r++) {
#pragma unroll
            for (int i = 0; i < 16; i++) st[r][i] = 0.f;
#pragma unroll
            for (int c = 0; c < 4; c++) {
                short8_t kf = *(const short8_a*)&kc[(r * 32 + l31) * 64 + ((2 * c + hi) ^ e) * 8];
                st[r] = __builtin_amdgcn_mfma_f32_32x32x16_bf16(kf, qf[c], st[r], 0, 0, 0);
            }
        }

        // ---- online softmax, defer-max (T13, exp2 domain, THR=8 -> p <= 256) ----
        float pmax = fmaxf(max16(st[0]), max16(st[1]));
        pmax = fmaxf(pmax, __shfl_xor(pmax, 32));
        if (__any(pmax > mrow + 8.f)) {
            float mn = fmaxf(mrow, pmax);
            float sc = exp2f(mrow - mn);
            mrow = mn;
            lacc[0] *= sc;
#pragma unroll
            for (int dd = 0; dd < 2; dd++)
#pragma unroll
                for (int i = 0; i < 16; i++) oacc[dd][i] *= sc;
        }
#pragma unroll
        for (int r = 0; r < 2; r++)
#pragma unroll
            for (int i = 0; i < 16; i++) st[r][i] = exp2f(st[r][i] - mrow);

        // ---- P pack (cvt_pk) + permlane32_swap -> PV B-frags, all in-register ----
#pragma unroll
        for (int r = 0; r < 2; r++) {
            unsigned pk8[8];
#pragma unroll
            for (int u = 0; u < 8; u++) {
                unsigned t;
                asm("v_cvt_pk_bf16_f32 %0, %1, %2" : "=v"(t) : "v"(st[r][2 * u]), "v"(st[r][2 * u + 1]));
                pk8[u] = t;
            }
#pragma unroll
            for (int cc = 0; cc < 2; cc++) {
                unsigned A0 = pk8[4 * cc + 0], B0 = pk8[4 * cc + 2];
                unsigned A1 = pk8[4 * cc + 1], B1 = pk8[4 * cc + 3];
                asm("v_permlane32_swap_b32 %0, %1" : "+v"(A0), "+v"(B0));
                asm("v_permlane32_swap_b32 %0, %1" : "+v"(A1), "+v"(B1));
                u32x4 pu = {A0, A1, B0, B1};
                short8_t pf = __builtin_bit_cast(short8_t, pu);
                // row-sum on the MFMA pipe: all-ones A => every row = sum_k P[k][q]
                lacc = __builtin_amdgcn_mfma_f32_32x32x16_bf16(ones, pf, lacc, 0, 0, 0);
#pragma unroll
                for (int dd = 0; dd < 2; dd++) {
                    short8_t vf = *(const short8_a*)&vc[(dd * 32 + l31) * 64 +
                                                        ((4 * r + 2 * cc + hi) ^ e) * 8];
                    oacc[dd] = __builtin_amdgcn_mfma_f32_32x32x16_bf16(vf, pf, oacc[dd], 0, 0, 0);
                }
            }
        }

        if (it + 1 < 32) {  // write next tile into the other buffer
            *(short8_a*)&kn[srow0 * 64 + kslot0] = kpre[0];
            *(short8_a*)&kn[srow1 * 64 + kslot1] = kpre[1];
            *(short8_a*)&vn[srow0 * 64 + kslot0] = vpre[0];
            *(short8_a*)&vn[srow1 * 64 + kslot1] = vpre[1];
        }
    };

    for (int it = 0; it < 32; it += 2) {
        body(Ks[0], Vs[0], Ks[1], Vs[1], it);
        body(Ks[1], Vs[1], Ks[0], Vs[0], it + 1);
    }

    // ---- epilogue: lane holds O^T[d][q=l31], d = (reg&3)+8*(reg>>2)+4*hi+32*dd ----
    float rl = 1.0f / lacc[0];
#pragma unroll
    for (int dd = 0; dd < 2; dd++)
#pragma unroll
        for (int g = 0; g < 4; g++) {
            short4_t o4;
#pragma unroll
            for (int i = 0; i < 4; i++) o4[i] = f2bf(oacc[dd][4 * g + i] * rl);
            *(short4_a*)&O[(qrow * 2 + b) * 1024 + hh * 64 + dd * 32 + g * 8 + hi * 4] = o4;
        }
}

extern "C" void kernel_launch(void* const* d_in, const int* in_sizes, int n_in,
                              void* d_out, int out_size, void* d_ws, size_t ws_size,
                              hipStream_t stream) {
    const float* query = (const float*)d_in[0];
    const float* Wq = (const float*)d_in[1];
    const float* bq = (const float*)d_in[2];
    const float* Wk = (const float*)d_in[3];
    const float* bk = (const float*)d_in[4];
    const float* Wv = (const float*)d_in[5];
    const float* bv = (const float*)d_in[6];
    const float* Wo = (const float*)d_in[7];
    const float* bo = (const float*)d_in[8];

    // ws layout (shorts). Total = 20,971,520 shorts = 40 MB
    short* Xbf = (short*)d_ws;        // 4096x1024 bf16 query (8 MB) -- reused as attn out
    short* Wqb = Xbf + 4194304;       // Wq|Wk|Wv contiguous = fused [3072][1024]
    short* Wkb = Wqb + 1048576;
    short* Wvb = Wkb + 1048576;
    short* Wob = Wvb + 1048576;
    short* Qb = Wob + 1048576;        // [B,H,T,D] 8 MB
    short* Kb = Qb + 4194304;         // [B,H,T,D] 8 MB
    short* Vtb = Kb + 4194304;        // [B,H,D,T] 8 MB
    short* attnb = Xbf;               // alias: Xbf dead after QKV projection

    cvt_kernel<<<2048, 256, 0, stream>>>(query, Xbf, 4194304);
    cvt_w4<<<dim3(512, 4), 256, 0, stream>>>(Wq, Wk, Wv, Wo, Wqb, Wkb, Wvb, Wob);

    // fused QKV: M=4096, N=3072, 128x128 tiles -> 768 blocks (3/CU)
    gemm_lds<128, 128, 4><<<dim3(24, 32), 256, 0, stream>>>(Xbf, Wqb, bq, bk, bv,
                                                            Qb, Kb, Vtb, nullptr);

    flash_attn<<<dim3(16, 32), 256, 0, stream>>>(Qb, Kb, Vtb, attnb);

    // O-proj: M=4096, N=1024, 64x128 tiles -> 512 blocks (2/CU)
    gemm_lds<64, 128, 3><<<dim3(8, 64), 256, 0, stream>>>(attnb, Wob, bo, nullptr, nullptr,
                                                          nullptr, nullptr, nullptr, (float*)d_out);
}